// Round 1
// baseline (754.055 us; speedup 1.0000x reference)
//
#include <hip/hip_runtime.h>
#include <hip/hip_bf16.h>

#define NATC  1024
#define BATCH 4
#define MNTC  200
#define M1C   100
#define M2C   16
#define FHC   240
#define KT    160

__device__ __forceinline__ float fast_tanh(float x){
    float e = __expf(2.0f * x);
    return 1.0f - __fdividef(2.0f, e + 1.0f);
}

// ---------------- partition atoms by type (deterministic) ----------------
__global__ __launch_bounds__(256) void part_kernel(const int* __restrict__ tmap,
                                                   int* __restrict__ idx,
                                                   int* __restrict__ counts){
    __shared__ int s0[256], s1[256];
    const int tid = threadIdx.x;
    int ty[4]; int c0 = 0, c1 = 0;
    #pragma unroll
    for (int r = 0; r < 4; ++r){
        ty[r] = tmap[tid*4 + r];
        if (ty[r] == 0) c0++; else c1++;
    }
    s0[tid] = c0; s1[tid] = c1;
    __syncthreads();
    for (int off = 1; off < 256; off <<= 1){
        int v0 = (tid >= off) ? s0[tid-off] : 0;
        int v1 = (tid >= off) ? s1[tid-off] : 0;
        __syncthreads();
        s0[tid] += v0; s1[tid] += v1;
        __syncthreads();
    }
    int e0 = s0[tid] - c0, e1 = s1[tid] - c1;
    #pragma unroll
    for (int r = 0; r < 4; ++r){
        int n = tid*4 + r;
        if (ty[r] == 0) idx[e0++] = n; else idx[NATC + e1++] = n;
    }
    if (tid == 255){ counts[0] = s0[255]; counts[1] = s1[255]; }
}

// ---------------- embedding net + xyz + DR ----------------
__global__ __launch_bounds__(256) void embed_kernel(
    const float4* __restrict__ imdr,
    const float4* __restrict__ davg,
    const float4* __restrict__ dstd,
    const int*    __restrict__ tmap,
    const float*  __restrict__ tv,
    const float*  __restrict__ tW0,
    const float*  __restrict__ tb0,
    const float*  __restrict__ eW0,
    const float*  __restrict__ eb0,
    const float*  __restrict__ eW1,
    const float*  __restrict__ eb1,
    const float*  __restrict__ eW2,
    const float*  __restrict__ eb2,
    float*        __restrict__ DRout)
{
    __shared__ float tf_s[16];
    __shared__ float Ri_s[MNTC][4];
    __shared__ float G_s[MNTC][52];       // chunk of 50 (+2 pad -> 208B rows, 16B aligned)
    __shared__ float xyz_s[4][M1C];

    const int tid = threadIdx.x;
    const int a   = blockIdx.x;           // a = b*1024 + n
    const int n   = a & (NATC - 1);
    const int itype = tmap[n];

    // type-embedding features: tanh(tv@tW0+tb0) + concat([tv,tv])  (8 == 2*4 resnet!)
    if (tid < 16){
        int t = tid >> 3, f = tid & 7;
        float s = tb0[f];
        #pragma unroll
        for (int p = 0; p < 4; ++p) s = fmaf(tv[t*4+p], tW0[p*8+f], s);
        tf_s[tid] = fast_tanh(s) + tv[t*4 + (f & 3)];
    }

    const int j = tid;
    float rin[4];
    if (j < MNTC){
        float4 dr = imdr[(size_t)a*MNTC + j];
        float r  = dr.x;
        float rs = (r > 1e-5f) ? r : 1.0f;
        float ir = __fdividef(1.0f, rs);
        float u  = (r - 0.5f) * (1.0f/5.5f);
        float u2 = u*u, u3 = u2*u;
        float smid = ir * (u3 * (-6.0f*u2 + 15.0f*u - 10.0f) + 1.0f);
        float S = 0.0f;
        if (r > 0.0f && r < 0.5f)       S = ir;
        else if (r >= 0.5f && r < 6.0f) S = smid;
        bool msk = fabsf(r) > 1e-5f;
        float R0 = S;
        float R1 = msk ? S * dr.y * ir : 0.0f;
        float R2 = msk ? S * dr.z * ir : 0.0f;
        float R3 = msk ? S * dr.w * ir : 0.0f;
        float4 av = davg[itype*MNTC + j];
        float4 sv = dstd[itype*MNTC + j];
        rin[0] = __fdividef(R0 - av.x, sv.x);
        rin[1] = __fdividef(R1 - av.y, sv.y);
        rin[2] = __fdividef(R2 - av.z, sv.z);
        rin[3] = __fdividef(R3 - av.w, sv.w);
        Ri_s[j][0] = rin[0];
        Ri_s[j][1] = rin[1];
        Ri_s[j][2] = rin[2];
        Ri_s[j][3] = rin[3];
    }
    __syncthreads();   // tf_s + Ri_s visible

    // embedding MLP, fully unrolled, weights via uniform scalar loads
    float h1[25];
    float h2[50];
    if (j < MNTC){
        float xf[8];
        const int tb = (j >= 100) ? 8 : 0;
        #pragma unroll
        for (int f = 0; f < 8; ++f) xf[f] = tf_s[tb + f];
        const float x0 = rin[0];

        float s1[25];
        #pragma unroll
        for (int o = 0; o < 25; ++o) s1[o] = fmaf(x0, eW0[o], eb0[o]);
        #pragma unroll
        for (int k = 0; k < 8; ++k){
            float hv = xf[k];
            #pragma unroll
            for (int o = 0; o < 25; ++o) s1[o] = fmaf(hv, eW0[(k+1)*25 + o], s1[o]);
        }
        #pragma unroll
        for (int o = 0; o < 25; ++o) h1[o] = fast_tanh(s1[o]);

        float s2[50];
        #pragma unroll
        for (int o = 0; o < 50; ++o) s2[o] = eb1[o];
        #pragma unroll
        for (int k = 0; k < 25; ++k){
            float hv = h1[k];
            #pragma unroll
            for (int o = 0; o < 50; ++o) s2[o] = fmaf(hv, eW1[k*50 + o], s2[o]);
        }
        #pragma unroll
        for (int o = 0; o < 50; ++o) h2[o] = fast_tanh(s2[o]) + h1[o % 25];
    }

    // layer 3 in two chunks of 50 outputs; reduce into xyz per chunk
    for (int c = 0; c < 2; ++c){
        float g[50];
        if (j < MNTC){
            #pragma unroll
            for (int o = 0; o < 50; ++o) g[o] = eb2[c*50 + o];
            #pragma unroll
            for (int k = 0; k < 50; ++k){
                float hv = h2[k];
                #pragma unroll
                for (int o = 0; o < 50; ++o) g[o] = fmaf(hv, eW2[k*100 + c*50 + o], g[o]);
            }
            #pragma unroll
            for (int o = 0; o < 50; ++o) g[o] = fast_tanh(g[o]) + h2[o];  // m%50 == o for both chunks
        }
        __syncthreads();     // previous chunk's reduce readers done
        if (j < MNTC){
            #pragma unroll
            for (int o = 0; o < 50; ++o) G_s[j][o] = g[o];
        }
        __syncthreads();
        if (tid < 200){
            const int d  = tid / 50;
            const int mm = tid - d*50;
            float acc = 0.0f;
            #pragma unroll 8
            for (int jj = 0; jj < MNTC; ++jj)
                acc = fmaf(G_s[jj][mm], Ri_s[jj][d], acc);
            xyz_s[d][c*50 + mm] = acc * (1.0f / (float)MNTC);
        }
    }
    __syncthreads();

    // DR[m][q] = sum_d xyz[d][m]*xyz[d][q], q < 16
    for (int i = tid; i < M1C*M2C; i += 256){
        int m = i >> 4, q = i & 15;
        float s = 0.0f;
        #pragma unroll
        for (int d = 0; d < 4; ++d) s = fmaf(xyz_s[d][m], xyz_s[d][q], s);
        DRout[(size_t)a*(M1C*M2C) + i] = s;
    }
}

// ---------------- fitting net (type-grouped atom tiles) ----------------
__global__ __launch_bounds__(256) void fit_kernel(
    const float* __restrict__ DRin,
    const int*   __restrict__ idx,
    const int*   __restrict__ counts,
    const float* __restrict__ fW0, const float* __restrict__ fb0,
    const float* __restrict__ fW1, const float* __restrict__ fb1,
    const float* __restrict__ fW2, const float* __restrict__ fb2,
    const float* __restrict__ fWf, const float* __restrict__ fbf,
    float* __restrict__ out)     // out[0..3]=Etot, out[4..]=Ei (B,NAT)
{
    const int bid = blockIdx.x;
    const int g = bid & 63;
    const int t = (bid >> 6) & 1;
    const int b = bid >> 7;
    const int cnt  = counts[t];
    const int base = g * 16;
    if (base >= cnt) return;
    const int na = min(16, cnt - base);

    __shared__ __align__(16) float DRs[16][KT];
    __shared__ __align__(16) float hA[16][FHC];
    __shared__ __align__(16) float hB[16][FHC];
    __shared__ int ns[16];

    const int tid = threadIdx.x;
    if (tid < 16) ns[tid] = (tid < na) ? idx[t*NATC + base + tid] : 0;
    __syncthreads();

    const int  ow = min(tid, FHC - 1);
    const bool oa = tid < FHC;

    // ---- L0: 1600 -> 240 ----
    float acc[16];
    #pragma unroll
    for (int ai = 0; ai < 16; ++ai) acc[ai] = fb0[t*FHC + ow];

    const float* w0p = fW0 + (size_t)t*1600*FHC + ow;
    for (int kt = 0; kt < 1600; kt += KT){
        for (int e2 = tid; e2 < 16*KT; e2 += 256){
            int ai = e2 / KT;
            int kk = e2 - ai*KT;
            DRs[ai][kk] = (ai < na) ? DRin[(size_t)(b*NATC + ns[ai])*1600 + kt + kk] : 0.0f;
        }
        __syncthreads();
        #pragma unroll 2
        for (int kk = 0; kk < KT; kk += 4){
            float w0 = w0p[(size_t)(kt+kk+0)*FHC];
            float w1 = w0p[(size_t)(kt+kk+1)*FHC];
            float w2 = w0p[(size_t)(kt+kk+2)*FHC];
            float w3 = w0p[(size_t)(kt+kk+3)*FHC];
            #pragma unroll
            for (int ai = 0; ai < 16; ++ai){
                float4 dv = *(const float4*)&DRs[ai][kk];
                float t0 = fmaf(dv.x, w0, acc[ai]);
                t0 = fmaf(dv.y, w1, t0);
                t0 = fmaf(dv.z, w2, t0);
                acc[ai] = fmaf(dv.w, w3, t0);
            }
        }
        __syncthreads();
    }
    if (oa){
        #pragma unroll
        for (int ai = 0; ai < 16; ++ai) hA[ai][ow] = fast_tanh(acc[ai]);
    }
    __syncthreads();

    // ---- L1: 240 -> 240 (+resnet) ----
    float a2[16];
    #pragma unroll
    for (int ai = 0; ai < 16; ++ai) a2[ai] = fb1[t*FHC + ow];
    const float* w1p = fW1 + (size_t)t*FHC*FHC + ow;
    for (int k = 0; k < FHC; k += 4){
        float w0 = w1p[(k+0)*FHC];
        float w1 = w1p[(k+1)*FHC];
        float w2 = w1p[(k+2)*FHC];
        float w3 = w1p[(k+3)*FHC];
        #pragma unroll
        for (int ai = 0; ai < 16; ++ai){
            float4 hv = *(const float4*)&hA[ai][k];
            float t0 = fmaf(hv.x, w0, a2[ai]);
            t0 = fmaf(hv.y, w1, t0);
            t0 = fmaf(hv.z, w2, t0);
            a2[ai] = fmaf(hv.w, w3, t0);
        }
    }
    if (oa){
        #pragma unroll
        for (int ai = 0; ai < 16; ++ai) hB[ai][ow] = fast_tanh(a2[ai]) + hA[ai][ow];
    }
    __syncthreads();

    // ---- L2: 240 -> 240 (+resnet) ----
    float a3[16];
    #pragma unroll
    for (int ai = 0; ai < 16; ++ai) a3[ai] = fb2[t*FHC + ow];
    const float* w2p = fW2 + (size_t)t*FHC*FHC + ow;
    for (int k = 0; k < FHC; k += 4){
        float w0 = w2p[(k+0)*FHC];
        float w1 = w2p[(k+1)*FHC];
        float w2 = w2p[(k+2)*FHC];
        float w3 = w2p[(k+3)*FHC];
        #pragma unroll
        for (int ai = 0; ai < 16; ++ai){
            float4 hv = *(const float4*)&hB[ai][k];
            float t0 = fmaf(hv.x, w0, a3[ai]);
            t0 = fmaf(hv.y, w1, t0);
            t0 = fmaf(hv.z, w2, t0);
            a3[ai] = fmaf(hv.w, w3, t0);
        }
    }
    float h3[16];
    #pragma unroll
    for (int ai = 0; ai < 16; ++ai) h3[ai] = fast_tanh(a3[ai]) + hB[ai][ow];

    // ---- final dot with fWf + Ei/Etot ----
    float wf = fWf[t*FHC + ow];
    float* red = &hA[0][0];            // reuse hA as [240][16] scratch
    if (oa){
        #pragma unroll
        for (int ai = 0; ai < 16; ++ai) red[ow*16 + ai] = h3[ai] * wf;
    }
    __syncthreads();
    float ee = 0.0f;
    if (tid < na){
        float e = fbf[t];
        for (int oo = 0; oo < FHC; ++oo) e += red[oo*16 + tid];
        out[4 + b*NATC + ns[tid]] = e;
        ee = e;
    }
    if (tid < 16){
        #pragma unroll
        for (int off = 8; off >= 1; off >>= 1) ee += __shfl_down(ee, off, 16);
        if (tid == 0) atomicAdd(&out[b], ee);
    }
}

extern "C" void kernel_launch(void* const* d_in, const int* in_sizes, int n_in,
                              void* d_out, int out_size, void* d_ws, size_t ws_size,
                              hipStream_t stream)
{
    (void)in_sizes; (void)n_in; (void)out_size; (void)ws_size;
    const int*   tmap = (const int*)d_in[1];
    const float* imdr = (const float*)d_in[3];
    const float* davg = (const float*)d_in[5];
    const float* dstd = (const float*)d_in[6];
    const float* tv   = (const float*)d_in[7];
    const float* tW0  = (const float*)d_in[8];
    const float* tb0  = (const float*)d_in[9];
    const float* eW0  = (const float*)d_in[10];
    const float* eb0  = (const float*)d_in[11];
    const float* eW1  = (const float*)d_in[12];
    const float* eb1  = (const float*)d_in[13];
    const float* eW2  = (const float*)d_in[14];
    const float* eb2  = (const float*)d_in[15];
    const float* fW0  = (const float*)d_in[16];
    const float* fb0  = (const float*)d_in[17];
    const float* fW1  = (const float*)d_in[18];
    const float* fb1  = (const float*)d_in[19];
    const float* fW2  = (const float*)d_in[20];
    const float* fb2  = (const float*)d_in[21];
    const float* fWf  = (const float*)d_in[22];
    const float* fbf  = (const float*)d_in[23];
    float* out = (float*)d_out;

    int*   counts = (int*)d_ws;
    int*   idx    = (int*)((char*)d_ws + 64);
    float* DRws   = (float*)((char*)d_ws + 16384);   // 4096*1600 floats = 26.2 MB

    hipMemsetAsync(d_out, 0, 4*sizeof(float), stream);   // Etot accumulators
    part_kernel<<<1, 256, 0, stream>>>(tmap, idx, counts);
    embed_kernel<<<BATCH*NATC, 256, 0, stream>>>(
        (const float4*)imdr, (const float4*)davg, (const float4*)dstd, tmap,
        tv, tW0, tb0, eW0, eb0, eW1, eb1, eW2, eb2, DRws);
    fit_kernel<<<512, 256, 0, stream>>>(
        DRws, idx, counts, fW0, fb0, fW1, fb1, fW2, fb2, fWf, fbf, out);
}

// Round 2
// 534.597 us; speedup vs baseline: 1.4105x; 1.4105x over previous
//
#include <hip/hip_runtime.h>
#include <hip/hip_bf16.h>

#define NATC  1024
#define BATCH 4
#define MNTC  200
#define M1C   100
#define M2C   16
#define FHC   240
#define KPAD  256
#define HSTR  264   // LDS h row stride in bf16 (528B: 2-way bank aliasing = free)

typedef __attribute__((ext_vector_type(8))) short bf16x8;
typedef __attribute__((ext_vector_type(4))) float f32x4;

__device__ __forceinline__ float fast_tanh(float x){
    float e = __expf(2.0f * x);
    return 1.0f - __fdividef(2.0f, e + 1.0f);
}

__device__ __forceinline__ unsigned short f2bf(float x){
    __hip_bfloat16 h = __float2bfloat16(x);
    return *reinterpret_cast<unsigned short*>(&h);
}

// ---------------- partition atoms by type (deterministic) ----------------
__global__ __launch_bounds__(256) void part_kernel(const int* __restrict__ tmap,
                                                   int* __restrict__ idx,
                                                   int* __restrict__ counts){
    __shared__ int s0[256], s1[256];
    const int tid = threadIdx.x;
    int ty[4]; int c0 = 0, c1 = 0;
    #pragma unroll
    for (int r = 0; r < 4; ++r){
        ty[r] = tmap[tid*4 + r];
        if (ty[r] == 0) c0++; else c1++;
    }
    s0[tid] = c0; s1[tid] = c1;
    __syncthreads();
    for (int off = 1; off < 256; off <<= 1){
        int v0 = (tid >= off) ? s0[tid-off] : 0;
        int v1 = (tid >= off) ? s1[tid-off] : 0;
        __syncthreads();
        s0[tid] += v0; s1[tid] += v1;
        __syncthreads();
    }
    int e0 = s0[tid] - c0, e1 = s1[tid] - c1;
    #pragma unroll
    for (int r = 0; r < 4; ++r){
        int n = tid*4 + r;
        if (ty[r] == 0) idx[e0++] = n; else idx[NATC + e1++] = n;
    }
    if (tid == 255){ counts[0] = s0[255]; counts[1] = s1[255]; }
}

// ---------------- weight convert+transpose to bf16 ----------------
// w0t[t][n][k] (k<1600) from fW0[t][k][n]
__global__ __launch_bounds__(256) void conv_w0_kernel(const float* __restrict__ fW0,
                                                      unsigned short* __restrict__ w0t){
    int i = blockIdx.x*256 + threadIdx.x;           // over [t*240+n][1600]
    if (i >= 2*FHC*1600) return;
    int k  = i % 1600;
    int tn = i / 1600;
    int t  = tn / FHC;
    int n  = tn % FHC;
    w0t[i] = f2bf(fW0[((size_t)t*1600 + k)*FHC + n]);
}

// w1t/w2t[t][n][k] (k padded to 256 with zeros) from fW{1,2}[t][k][n]
__global__ __launch_bounds__(256) void conv_w12_kernel(const float* __restrict__ fW1,
                                                       const float* __restrict__ fW2,
                                                       unsigned short* __restrict__ w1t,
                                                       unsigned short* __restrict__ w2t){
    int i = blockIdx.x*256 + threadIdx.x;           // over 2 * [t*240+n][256]
    if (i >= 2*2*FHC*KPAD) return;
    int which = i / (2*FHC*KPAD);
    int j  = i % (2*FHC*KPAD);
    int k  = j % KPAD;
    int tn = j / KPAD;
    int t  = tn / FHC;
    int n  = tn % FHC;
    const float* src = which ? fW2 : fW1;
    unsigned short* dst = which ? w2t : w1t;
    dst[j] = (k < FHC) ? f2bf(src[((size_t)t*FHC + k)*FHC + n]) : (unsigned short)0;
}

// ---------------- embedding net + xyz + DR (bf16 out) ----------------
__global__ __launch_bounds__(256) void embed_kernel(
    const float4* __restrict__ imdr,
    const float4* __restrict__ davg,
    const float4* __restrict__ dstd,
    const int*    __restrict__ tmap,
    const float*  __restrict__ tv,
    const float*  __restrict__ tW0,
    const float*  __restrict__ tb0,
    const float*  __restrict__ eW0,
    const float*  __restrict__ eb0,
    const float*  __restrict__ eW1,
    const float*  __restrict__ eb1,
    const float*  __restrict__ eW2,
    const float*  __restrict__ eb2,
    unsigned short* __restrict__ DRout)
{
    __shared__ float tf_s[16];
    __shared__ float Ri_s[MNTC][4];
    __shared__ float G_s[MNTC][52];
    __shared__ float xyz_s[4][M1C];

    const int tid = threadIdx.x;
    const int a   = blockIdx.x;           // a = b*1024 + n
    const int n   = a & (NATC - 1);
    const int itype = tmap[n];

    if (tid < 16){
        int t = tid >> 3, f = tid & 7;
        float s = tb0[f];
        #pragma unroll
        for (int p = 0; p < 4; ++p) s = fmaf(tv[t*4+p], tW0[p*8+f], s);
        tf_s[tid] = fast_tanh(s) + tv[t*4 + (f & 3)];
    }

    const int j = tid;
    float rin[4];
    if (j < MNTC){
        float4 dr = imdr[(size_t)a*MNTC + j];
        float r  = dr.x;
        float rs = (r > 1e-5f) ? r : 1.0f;
        float ir = __fdividef(1.0f, rs);
        float u  = (r - 0.5f) * (1.0f/5.5f);
        float u2 = u*u, u3 = u2*u;
        float smid = ir * (u3 * (-6.0f*u2 + 15.0f*u - 10.0f) + 1.0f);
        float S = 0.0f;
        if (r > 0.0f && r < 0.5f)       S = ir;
        else if (r >= 0.5f && r < 6.0f) S = smid;
        bool msk = fabsf(r) > 1e-5f;
        float R0 = S;
        float R1 = msk ? S * dr.y * ir : 0.0f;
        float R2 = msk ? S * dr.z * ir : 0.0f;
        float R3 = msk ? S * dr.w * ir : 0.0f;
        float4 av = davg[itype*MNTC + j];
        float4 sv = dstd[itype*MNTC + j];
        rin[0] = __fdividef(R0 - av.x, sv.x);
        rin[1] = __fdividef(R1 - av.y, sv.y);
        rin[2] = __fdividef(R2 - av.z, sv.z);
        rin[3] = __fdividef(R3 - av.w, sv.w);
        Ri_s[j][0] = rin[0];
        Ri_s[j][1] = rin[1];
        Ri_s[j][2] = rin[2];
        Ri_s[j][3] = rin[3];
    }
    __syncthreads();

    float h1[25];
    float h2[50];
    if (j < MNTC){
        float xf[8];
        const int tb = (j >= 100) ? 8 : 0;
        #pragma unroll
        for (int f = 0; f < 8; ++f) xf[f] = tf_s[tb + f];
        const float x0 = rin[0];

        float s1[25];
        #pragma unroll
        for (int o = 0; o < 25; ++o) s1[o] = fmaf(x0, eW0[o], eb0[o]);
        #pragma unroll
        for (int k = 0; k < 8; ++k){
            float hv = xf[k];
            #pragma unroll
            for (int o = 0; o < 25; ++o) s1[o] = fmaf(hv, eW0[(k+1)*25 + o], s1[o]);
        }
        #pragma unroll
        for (int o = 0; o < 25; ++o) h1[o] = fast_tanh(s1[o]);

        float s2[50];
        #pragma unroll
        for (int o = 0; o < 50; ++o) s2[o] = eb1[o];
        #pragma unroll
        for (int k = 0; k < 25; ++k){
            float hv = h1[k];
            #pragma unroll
            for (int o = 0; o < 50; ++o) s2[o] = fmaf(hv, eW1[k*50 + o], s2[o]);
        }
        #pragma unroll
        for (int o = 0; o < 50; ++o) h2[o] = fast_tanh(s2[o]) + h1[o % 25];
    }

    for (int c = 0; c < 2; ++c){
        float g[50];
        if (j < MNTC){
            #pragma unroll
            for (int o = 0; o < 50; ++o) g[o] = eb2[c*50 + o];
            #pragma unroll
            for (int k = 0; k < 50; ++k){
                float hv = h2[k];
                #pragma unroll
                for (int o = 0; o < 50; ++o) g[o] = fmaf(hv, eW2[k*100 + c*50 + o], g[o]);
            }
            #pragma unroll
            for (int o = 0; o < 50; ++o) g[o] = fast_tanh(g[o]) + h2[o];
        }
        __syncthreads();
        if (j < MNTC){
            #pragma unroll
            for (int o = 0; o < 50; ++o) G_s[j][o] = g[o];
        }
        __syncthreads();
        if (tid < 200){
            const int d  = tid / 50;
            const int mm = tid - d*50;
            float acc = 0.0f;
            #pragma unroll 8
            for (int jj = 0; jj < MNTC; ++jj)
                acc = fmaf(G_s[jj][mm], Ri_s[jj][d], acc);
            xyz_s[d][c*50 + mm] = acc * (1.0f / (float)MNTC);
        }
    }
    __syncthreads();

    // DR[m][q] -> bf16
    for (int i = tid; i < M1C*M2C; i += 256){
        int m = i >> 4, q = i & 15;
        float s = 0.0f;
        #pragma unroll
        for (int d = 0; d < 4; ++d) s = fmaf(xyz_s[d][m], xyz_s[d][q], s);
        DRout[(size_t)a*(M1C*M2C) + i] = f2bf(s);
    }
}

// ---------------- fitting net: bf16 MFMA, 16 atoms/block, 4 waves ----------------
__global__ __launch_bounds__(256) void fitm_kernel(
    const unsigned short* __restrict__ DRbf,   // [4096][1600] bf16
    const int*   __restrict__ idx,
    const int*   __restrict__ counts,
    const unsigned short* __restrict__ w0t,    // [2][240][1600]
    const unsigned short* __restrict__ w1t,    // [2][240][256] (zero-padded k>=240)
    const unsigned short* __restrict__ w2t,    // [2][240][256]
    const float* __restrict__ fb0,
    const float* __restrict__ fb1,
    const float* __restrict__ fb2,
    const float* __restrict__ fWf,
    const float* __restrict__ fbf,
    float* __restrict__ out)     // out[0..3]=Etot, out[4..]=Ei
{
    const int bid = blockIdx.x;
    const int g = bid & 63;
    const int t = (bid >> 6) & 1;
    const int b = bid >> 7;
    const int cnt  = counts[t];
    const int base = g * 16;
    if (base >= cnt) return;
    const int na = min(16, cnt - base);

    __shared__ int ns[16];
    __shared__ unsigned short hA[16][HSTR];
    __shared__ unsigned short hB[16][HSTR];
    __shared__ float epart[4][16];

    const int tid  = threadIdx.x;
    const int lane = tid & 63;
    const int w    = tid >> 6;       // wave 0..3, owns n-cols [w*64, w*64+64)
    if (tid < 16) ns[tid] = idx[t*NATC + base + ((tid < na) ? tid : 0)];
    __syncthreads();

    const int lc = lane & 15;        // A-row / B-col / C-col selector
    const int lg = lane >> 4;        // k-group / C-row-group

    // per-tile setup
    int   ncol[4];  bool act[4];  float bias0[4];
    #pragma unroll
    for (int nt = 0; nt < 4; ++nt){
        ncol[nt] = w*64 + nt*16 + lc;
        act[nt]  = (w*64 + nt*16) < FHC;     // wave-uniform
        bias0[nt] = act[nt] ? fb0[t*FHC + ncol[nt]] : 0.0f;
    }

    const unsigned short* aptr0 = DRbf + ((size_t)(b*NATC + ns[lc]))*1600 + lg*8;
    const unsigned short* bptr0[4];
    #pragma unroll
    for (int nt = 0; nt < 4; ++nt)
        bptr0[nt] = act[nt] ? (w0t + ((size_t)(t*FHC + ncol[nt]))*1600 + lg*8) : w0t;

    // ---- L0: 1600 -> 240 ----
    f32x4 acc[4];
    #pragma unroll
    for (int nt = 0; nt < 4; ++nt){
        acc[nt][0] = bias0[nt]; acc[nt][1] = bias0[nt];
        acc[nt][2] = bias0[nt]; acc[nt][3] = bias0[nt];
    }
    #pragma unroll 2
    for (int ks = 0; ks < 50; ++ks){
        bf16x8 af = *(const bf16x8*)(aptr0 + ks*32);
        #pragma unroll
        for (int nt = 0; nt < 4; ++nt){
            if (act[nt]){
                bf16x8 bfg = *(const bf16x8*)(bptr0[nt] + ks*32);
                acc[nt] = __builtin_amdgcn_mfma_f32_16x16x32_bf16(af, bfg, acc[nt], 0, 0, 0);
            }
        }
    }
    // epilogue: h0 = tanh(acc); stage bf16 to hA (zero the K-pad cols)
    float h0r[4][4];
    #pragma unroll
    for (int nt = 0; nt < 4; ++nt){
        #pragma unroll
        for (int i = 0; i < 4; ++i){
            int row = lg*4 + i;
            if (act[nt]){
                h0r[nt][i] = fast_tanh(acc[nt][i]);
                hA[row][ncol[nt]] = f2bf(h0r[nt][i]);
            } else {
                h0r[nt][i] = 0.0f;
                hA[row][ncol[nt]] = 0;     // cols 240..255 zero pad
            }
        }
    }
    __syncthreads();

    // ---- L1: 240 -> 240 (+res), K padded to 256 ----
    f32x4 acc1[4];
    #pragma unroll
    for (int nt = 0; nt < 4; ++nt){
        float bv = act[nt] ? fb1[t*FHC + ncol[nt]] : 0.0f;
        acc1[nt][0] = bv; acc1[nt][1] = bv; acc1[nt][2] = bv; acc1[nt][3] = bv;
    }
    const unsigned short* b1p[4];
    #pragma unroll
    for (int nt = 0; nt < 4; ++nt)
        b1p[nt] = act[nt] ? (w1t + ((size_t)(t*FHC + ncol[nt]))*KPAD + lg*8) : w1t;
    #pragma unroll
    for (int ks = 0; ks < 8; ++ks){
        bf16x8 af = *(const bf16x8*)&hA[lc][ks*32 + lg*8];
        #pragma unroll
        for (int nt = 0; nt < 4; ++nt){
            if (act[nt]){
                bf16x8 bfg = *(const bf16x8*)(b1p[nt] + ks*32);
                acc1[nt] = __builtin_amdgcn_mfma_f32_16x16x32_bf16(af, bfg, acc1[nt], 0, 0, 0);
            }
        }
    }
    float h1r[4][4];
    #pragma unroll
    for (int nt = 0; nt < 4; ++nt){
        #pragma unroll
        for (int i = 0; i < 4; ++i){
            int row = lg*4 + i;
            if (act[nt]){
                h1r[nt][i] = fast_tanh(acc1[nt][i]) + h0r[nt][i];
                hB[row][ncol[nt]] = f2bf(h1r[nt][i]);
            } else {
                h1r[nt][i] = 0.0f;
                hB[row][ncol[nt]] = 0;
            }
        }
    }
    __syncthreads();

    // ---- L2: 240 -> 240 (+res) ----
    f32x4 acc2[4];
    #pragma unroll
    for (int nt = 0; nt < 4; ++nt){
        float bv = act[nt] ? fb2[t*FHC + ncol[nt]] : 0.0f;
        acc2[nt][0] = bv; acc2[nt][1] = bv; acc2[nt][2] = bv; acc2[nt][3] = bv;
    }
    const unsigned short* b2p[4];
    #pragma unroll
    for (int nt = 0; nt < 4; ++nt)
        b2p[nt] = act[nt] ? (w2t + ((size_t)(t*FHC + ncol[nt]))*KPAD + lg*8) : w2t;
    #pragma unroll
    for (int ks = 0; ks < 8; ++ks){
        bf16x8 af = *(const bf16x8*)&hB[lc][ks*32 + lg*8];
        #pragma unroll
        for (int nt = 0; nt < 4; ++nt){
            if (act[nt]){
                bf16x8 bfg = *(const bf16x8*)(b2p[nt] + ks*32);
                acc2[nt] = __builtin_amdgcn_mfma_f32_16x16x32_bf16(af, bfg, acc2[nt], 0, 0, 0);
            }
        }
    }

    // ---- final: e = sum_n h2*wf + fbf ----
    float p0 = 0.0f, p1 = 0.0f, p2 = 0.0f, p3 = 0.0f;
    #pragma unroll
    for (int nt = 0; nt < 4; ++nt){
        if (act[nt]){
            float wfv = fWf[t*FHC + ncol[nt]];
            float h;
            h = fast_tanh(acc2[nt][0]) + h1r[nt][0]; p0 = fmaf(h, wfv, p0);
            h = fast_tanh(acc2[nt][1]) + h1r[nt][1]; p1 = fmaf(h, wfv, p1);
            h = fast_tanh(acc2[nt][2]) + h1r[nt][2]; p2 = fmaf(h, wfv, p2);
            h = fast_tanh(acc2[nt][3]) + h1r[nt][3]; p3 = fmaf(h, wfv, p3);
        }
    }
    // reduce over the 16 lanes (lc) sharing this row-group
    #pragma unroll
    for (int off = 1; off < 16; off <<= 1){
        p0 += __shfl_xor(p0, off);
        p1 += __shfl_xor(p1, off);
        p2 += __shfl_xor(p2, off);
        p3 += __shfl_xor(p3, off);
    }
    if (lc == 0){
        epart[w][lg*4 + 0] = p0;
        epart[w][lg*4 + 1] = p1;
        epart[w][lg*4 + 2] = p2;
        epart[w][lg*4 + 3] = p3;
    }
    __syncthreads();
    if (tid < 16){
        float e = fbf[t] + epart[0][tid] + epart[1][tid] + epart[2][tid] + epart[3][tid];
        float ee = 0.0f;
        if (tid < na){
            out[4 + b*NATC + ns[tid]] = e;
            ee = e;
        }
        #pragma unroll
        for (int off = 8; off >= 1; off >>= 1) ee += __shfl_down(ee, off, 16);
        if (tid == 0) atomicAdd(&out[b], ee);
    }
}

extern "C" void kernel_launch(void* const* d_in, const int* in_sizes, int n_in,
                              void* d_out, int out_size, void* d_ws, size_t ws_size,
                              hipStream_t stream)
{
    (void)in_sizes; (void)n_in; (void)out_size; (void)ws_size;
    const int*   tmap = (const int*)d_in[1];
    const float* imdr = (const float*)d_in[3];
    const float* davg = (const float*)d_in[5];
    const float* dstd = (const float*)d_in[6];
    const float* tv   = (const float*)d_in[7];
    const float* tW0  = (const float*)d_in[8];
    const float* tb0  = (const float*)d_in[9];
    const float* eW0  = (const float*)d_in[10];
    const float* eb0  = (const float*)d_in[11];
    const float* eW1  = (const float*)d_in[12];
    const float* eb1  = (const float*)d_in[13];
    const float* eW2  = (const float*)d_in[14];
    const float* eb2  = (const float*)d_in[15];
    const float* fW0  = (const float*)d_in[16];
    const float* fb0  = (const float*)d_in[17];
    const float* fW1  = (const float*)d_in[18];
    const float* fb1  = (const float*)d_in[19];
    const float* fW2  = (const float*)d_in[20];
    const float* fb2  = (const float*)d_in[21];
    const float* fWf  = (const float*)d_in[22];
    const float* fbf  = (const float*)d_in[23];
    float* out = (float*)d_out;

    int*   counts = (int*)d_ws;
    int*   idx    = (int*)((char*)d_ws + 64);
    unsigned short* DRbf = (unsigned short*)((char*)d_ws + 16384);
    unsigned short* w0t  = DRbf + (size_t)BATCH*NATC*1600;   // 13,107,200 B
    unsigned short* w1t  = w0t + 2*FHC*1600;
    unsigned short* w2t  = w1t + 2*FHC*KPAD;

    hipMemsetAsync(d_out, 0, 4*sizeof(float), stream);
    part_kernel<<<1, 256, 0, stream>>>(tmap, idx, counts);
    conv_w0_kernel<<<(2*FHC*1600 + 255)/256, 256, 0, stream>>>(fW0, w0t);
    conv_w12_kernel<<<(2*2*FHC*KPAD + 255)/256, 256, 0, stream>>>(fW1, fW2, w1t, w2t);
    embed_kernel<<<BATCH*NATC, 256, 0, stream>>>(
        (const float4*)imdr, (const float4*)davg, (const float4*)dstd, tmap,
        tv, tW0, tb0, eW0, eb0, eW1, eb1, eW2, eb2, DRbf);
    fitm_kernel<<<512, 256, 0, stream>>>(
        DRbf, idx, counts, w0t, w1t, w2t, fb0, fb1, fb2, fWf, fbf, out);
}

// Round 3
// 429.227 us; speedup vs baseline: 1.7568x; 1.2455x over previous
//
#include <hip/hip_runtime.h>
#include <hip/hip_bf16.h>

#define NATC  1024
#define BATCH 4
#define MNTC  200
#define M1C   100
#define M2C   16
#define FHC   240
#define KPAD  256
#define HSTR  264   // fitm LDS h row stride (bf16)

typedef __attribute__((ext_vector_type(8))) short bf16x8;
typedef __attribute__((ext_vector_type(4))) float f32x4;

__device__ __forceinline__ float fast_tanh(float x){
    float e = __expf(2.0f * x);
    float r = __fdividef(1.0f, e + 1.0f);
    return fmaf(-2.0f, r, 1.0f);
}

__device__ __forceinline__ unsigned short f2bf(float x){
    __hip_bfloat16 h = __float2bfloat16(x);
    return *reinterpret_cast<unsigned short*>(&h);
}

__device__ __forceinline__ float bf2f(unsigned short u){
    unsigned int v = ((unsigned int)u) << 16;
    return *reinterpret_cast<float*>(&v);
}

// ---------------- partition atoms by type (deterministic) ----------------
__global__ __launch_bounds__(256) void part_kernel(const int* __restrict__ tmap,
                                                   int* __restrict__ idx,
                                                   int* __restrict__ counts){
    __shared__ int s0[256], s1[256];
    const int tid = threadIdx.x;
    int ty[4]; int c0 = 0, c1 = 0;
    #pragma unroll
    for (int r = 0; r < 4; ++r){
        ty[r] = tmap[tid*4 + r];
        if (ty[r] == 0) c0++; else c1++;
    }
    s0[tid] = c0; s1[tid] = c1;
    __syncthreads();
    for (int off = 1; off < 256; off <<= 1){
        int v0 = (tid >= off) ? s0[tid-off] : 0;
        int v1 = (tid >= off) ? s1[tid-off] : 0;
        __syncthreads();
        s0[tid] += v0; s1[tid] += v1;
        __syncthreads();
    }
    int e0 = s0[tid] - c0, e1 = s1[tid] - c1;
    #pragma unroll
    for (int r = 0; r < 4; ++r){
        int n = tid*4 + r;
        if (ty[r] == 0) idx[e0++] = n; else idx[NATC + e1++] = n;
    }
    if (tid == 255){ counts[0] = s0[255]; counts[1] = s1[255]; }
}

// ---------------- tiled transpose: src fp32 [2][K][N] -> dst bf16 [2][N][Kpad] ----------------
// Covers k in [0,Kpad) (zero-fills K..Kpad). Both phases coalesced via LDS tile.
__global__ __launch_bounds__(256) void transp_kernel(const float* __restrict__ src,
                                                     unsigned short* __restrict__ dst,
                                                     int K, int N, int Kpad, int nkt, int nnt){
    __shared__ float tile[64][65];
    const int tid = threadIdx.x;
    int bid = blockIdx.x;
    const int t  = bid / (nkt*nnt);
    bid -= t*nkt*nnt;
    const int kt = bid / nnt;
    const int nt = bid - kt*nnt;
    const float* s = src + (size_t)t*K*N;
    unsigned short* d = dst + (size_t)t*N*Kpad;

    const int c  = tid & 63;
    const int rg = tid >> 6;
    #pragma unroll
    for (int p = 0; p < 16; ++p){
        int row = p*4 + rg;                 // k within tile
        int gr = kt*64 + row, gc = nt*64 + c;
        tile[row][c] = (gr < K && gc < N) ? s[(size_t)gr*N + gc] : 0.0f;
    }
    __syncthreads();
    const int nn0 = tid >> 3;               // 0..31
    const int k8  = (tid & 7) * 8;
    #pragma unroll
    for (int p = 0; p < 2; ++p){
        int nn = p*32 + nn0;
        int gn = nt*64 + nn;
        int gk = kt*64 + k8;
        if (gn < N && gk < Kpad){
            unsigned short v[8];
            #pragma unroll
            for (int j = 0; j < 8; ++j) v[j] = f2bf(tile[k8+j][nn]);
            *(bf16x8*)(d + (size_t)gn*Kpad + gk) = *(bf16x8*)v;
        }
    }
}

// ---------------- small prep: type features + ew2t [112][64] bf16 ----------------
__global__ __launch_bounds__(256) void prep_kernel(const float* __restrict__ tv,
                                                   const float* __restrict__ tW0,
                                                   const float* __restrict__ tb0,
                                                   const float* __restrict__ eW2,
                                                   unsigned short* __restrict__ ew2t,
                                                   float* __restrict__ tf_g){
    const int tid = threadIdx.x;
    if (tid < 16){
        int t = tid >> 3, f = tid & 7;
        float s = tb0[f];
        #pragma unroll
        for (int p = 0; p < 4; ++p) s = fmaf(tv[t*4+p], tW0[p*8+f], s);
        tf_g[tid] = fast_tanh(s) + tv[t*4 + (f & 3)];
    }
    for (int i = tid; i < 112*64; i += 256){
        int n = i >> 6, k = i & 63;
        ew2t[i] = (n < M1C && k < 50) ? f2bf(eW2[(size_t)k*M1C + n]) : (unsigned short)0;
    }
}

// ---------------- embedding: L0/L1 per-thread fp32, L2 via MFMA, xyz in-register ----------------
__global__ __launch_bounds__(256, 2) void embed_kernel(
    const float4* __restrict__ imdr,
    const float4* __restrict__ davg,
    const float4* __restrict__ dstd,
    const int*    __restrict__ tmap,
    const float*  __restrict__ tf_g,
    const float*  __restrict__ eW0,
    const float*  __restrict__ eb0,
    const float*  __restrict__ eW1,
    const float*  __restrict__ eb1,
    const float*  __restrict__ eb2,
    const unsigned short* __restrict__ ew2t,
    unsigned short* __restrict__ DRout)
{
    __shared__ unsigned short H2s[256][72];   // bf16, cols 0..49 live, 50..63 zero
    __shared__ float Rif[256][4];             // fp32, rows 200..255 zero
    __shared__ float xyzp[4][4][112];         // wave partials
    __shared__ float xyzs[4][112];

    const int tid = threadIdx.x;
    const int a   = blockIdx.x;
    const int n   = a & (NATC - 1);
    const int itype = tmap[n];
    const int j = tid;

    // ---------- phase A: Ri + L0 + L1 (fp32, per-thread) ----------
    if (j < MNTC){
        float4 dr = imdr[(size_t)a*MNTC + j];
        float r  = dr.x;
        float rs = (r > 1e-5f) ? r : 1.0f;
        float ir = __fdividef(1.0f, rs);
        float u  = (r - 0.5f) * (1.0f/5.5f);
        float u2 = u*u, u3 = u2*u;
        float smid = ir * (u3 * (-6.0f*u2 + 15.0f*u - 10.0f) + 1.0f);
        float S = 0.0f;
        if (r > 0.0f && r < 0.5f)       S = ir;
        else if (r >= 0.5f && r < 6.0f) S = smid;
        bool msk = fabsf(r) > 1e-5f;
        float R0 = S;
        float R1 = msk ? S * dr.y * ir : 0.0f;
        float R2 = msk ? S * dr.z * ir : 0.0f;
        float R3 = msk ? S * dr.w * ir : 0.0f;
        float4 av = davg[itype*MNTC + j];
        float4 sv = dstd[itype*MNTC + j];
        float rin0 = __fdividef(R0 - av.x, sv.x);
        float rin1 = __fdividef(R1 - av.y, sv.y);
        float rin2 = __fdividef(R2 - av.z, sv.z);
        float rin3 = __fdividef(R3 - av.w, sv.w);
        Rif[j][0] = rin0; Rif[j][1] = rin1; Rif[j][2] = rin2; Rif[j][3] = rin3;

        float xf[8];
        const int tb = (j >= 100) ? 8 : 0;
        #pragma unroll
        for (int f = 0; f < 8; ++f) xf[f] = tf_g[tb + f];

        float h1[25];
        #pragma unroll
        for (int o = 0; o < 25; ++o) h1[o] = fmaf(rin0, eW0[o], eb0[o]);
        #pragma unroll
        for (int k = 0; k < 8; ++k){
            float hv = xf[k];
            #pragma unroll
            for (int o = 0; o < 25; ++o) h1[o] = fmaf(hv, eW0[(k+1)*25 + o], h1[o]);
        }
        #pragma unroll
        for (int o = 0; o < 25; ++o) h1[o] = fast_tanh(h1[o]);

        float h2[50];
        #pragma unroll
        for (int o = 0; o < 50; ++o) h2[o] = eb1[o];
        #pragma unroll
        for (int k = 0; k < 25; ++k){
            float hv = h1[k];
            #pragma unroll
            for (int o = 0; o < 50; ++o) h2[o] = fmaf(hv, eW1[k*50 + o], h2[o]);
        }
        #pragma unroll
        for (int o = 0; o < 50; ++o) h2[o] = fast_tanh(h2[o]) + h1[o % 25];

        // write H2 row (packed bf16 pairs), zero pad cols 50..63
        unsigned int* rowp = (unsigned int*)&H2s[j][0];
        #pragma unroll
        for (int c = 0; c < 25; ++c)
            rowp[c] = (unsigned int)f2bf(h2[2*c]) | ((unsigned int)f2bf(h2[2*c+1]) << 16);
        #pragma unroll
        for (int c = 25; c < 32; ++c) rowp[c] = 0u;
    } else {
        Rif[j][0] = 0.0f; Rif[j][1] = 0.0f; Rif[j][2] = 0.0f; Rif[j][3] = 0.0f;
        unsigned int* rowp = (unsigned int*)&H2s[j][0];
        #pragma unroll
        for (int c = 0; c < 32; ++c) rowp[c] = 0u;
    }
    __syncthreads();

    // ---------- phase B: L2 via MFMA (M=256, K=64, N=112) + xyz reduce ----------
    const int lane = tid & 63;
    const int w    = tid >> 6;
    const int lc   = lane & 15;
    const int lg   = lane >> 4;

    float bias[7];
    #pragma unroll
    for (int nt = 0; nt < 7; ++nt){
        int cg = nt*16 + lc;
        bias[nt] = (cg < M1C) ? eb2[cg] : 0.0f;
    }

    float xacc[7][4];
    #pragma unroll
    for (int nt = 0; nt < 7; ++nt)
        #pragma unroll
        for (int d = 0; d < 4; ++d) xacc[nt][d] = 0.0f;

    #pragma unroll
    for (int mi = 0; mi < 4; ++mi){
        const int mt = w + mi*4;
        const int rbase = mt*16 + lg*4;
        // Ri broadcast rows for this lane's 4 C-rows
        float4 rj[4];
        #pragma unroll
        for (int i = 0; i < 4; ++i) rj[i] = *(const float4*)&Rif[rbase + i][0];
        // A-frags (row = mt*16+lc)
        const unsigned short* arow = &H2s[mt*16 + lc][0];
        bf16x8 a0 = *(const bf16x8*)(arow + lg*8);
        bf16x8 a1 = *(const bf16x8*)(arow + 32 + lg*8);
        #pragma unroll
        for (int nt = 0; nt < 7; ++nt){
            const unsigned short* bp = ew2t + (size_t)(nt*16 + lc)*64 + lg*8;
            bf16x8 b0 = *(const bf16x8*)(bp);
            bf16x8 b1 = *(const bf16x8*)(bp + 32);
            f32x4 c;
            c[0] = bias[nt]; c[1] = bias[nt]; c[2] = bias[nt]; c[3] = bias[nt];
            c = __builtin_amdgcn_mfma_f32_16x16x32_bf16(a0, b0, c, 0, 0, 0);
            c = __builtin_amdgcn_mfma_f32_16x16x32_bf16(a1, b1, c, 0, 0, 0);
            const int cg = nt*16 + lc;
            const int rc = (cg >= 100) ? cg - 100 : ((cg >= 50) ? cg - 50 : cg);
            #pragma unroll
            for (int i = 0; i < 4; ++i){
                float g = fast_tanh(c[i]) + bf2f(H2s[rbase + i][rc]);
                xacc[nt][0] = fmaf(g, rj[i].x, xacc[nt][0]);
                xacc[nt][1] = fmaf(g, rj[i].y, xacc[nt][1]);
                xacc[nt][2] = fmaf(g, rj[i].z, xacc[nt][2]);
                xacc[nt][3] = fmaf(g, rj[i].w, xacc[nt][3]);
            }
        }
    }
    // reduce across the 4 lg groups
    #pragma unroll
    for (int nt = 0; nt < 7; ++nt){
        #pragma unroll
        for (int d = 0; d < 4; ++d){
            float v = xacc[nt][d];
            v += __shfl_xor(v, 16);
            v += __shfl_xor(v, 32);
            if (lane < 16) xyzp[w][d][nt*16 + lc] = v;
        }
    }
    __syncthreads();

    // ---------- phase C: combine wave partials ----------
    for (int i = tid; i < 4*112; i += 256){
        int d = i / 112, m = i - d*112;
        xyzs[d][m] = (xyzp[0][d][m] + xyzp[1][d][m] + xyzp[2][d][m] + xyzp[3][d][m])
                     * (1.0f / (float)MNTC);
    }
    __syncthreads();

    // ---------- phase D: DR = xyz^T @ xyz[:, :16] -> bf16 ----------
    for (int i = tid; i < M1C*M2C; i += 256){
        int m = i >> 4, q = i & 15;
        float s = 0.0f;
        #pragma unroll
        for (int d = 0; d < 4; ++d) s = fmaf(xyzs[d][m], xyzs[d][q], s);
        DRout[(size_t)a*(M1C*M2C) + i] = f2bf(s);
    }
}

// ---------------- fitting net: bf16 MFMA, 16 atoms/block, 4 waves ----------------
__global__ __launch_bounds__(256) void fitm_kernel(
    const unsigned short* __restrict__ DRbf,   // [4096][1600] bf16
    const int*   __restrict__ idx,
    const int*   __restrict__ counts,
    const unsigned short* __restrict__ w0t,    // [2][240][1600]
    const unsigned short* __restrict__ w1t,    // [2][240][256]
    const unsigned short* __restrict__ w2t,    // [2][240][256]
    const float* __restrict__ fb0,
    const float* __restrict__ fb1,
    const float* __restrict__ fb2,
    const float* __restrict__ fWf,
    const float* __restrict__ fbf,
    float* __restrict__ out)     // out[0..3]=Etot, out[4..]=Ei
{
    const int bid = blockIdx.x;
    const int g = bid & 63;
    const int t = (bid >> 6) & 1;
    const int b = bid >> 7;
    const int cnt  = counts[t];
    const int base = g * 16;
    if (base >= cnt) return;
    const int na = min(16, cnt - base);

    __shared__ int ns[16];
    __shared__ unsigned short hA[16][HSTR];
    __shared__ unsigned short hB[16][HSTR];
    __shared__ float epart[4][16];

    const int tid  = threadIdx.x;
    const int lane = tid & 63;
    const int w    = tid >> 6;
    if (tid < 16) ns[tid] = idx[t*NATC + base + ((tid < na) ? tid : 0)];
    __syncthreads();

    const int lc = lane & 15;
    const int lg = lane >> 4;

    int   ncol[4];  bool act[4];  float bias0[4];
    #pragma unroll
    for (int nt = 0; nt < 4; ++nt){
        ncol[nt] = w*64 + nt*16 + lc;
        act[nt]  = (w*64 + nt*16) < FHC;
        bias0[nt] = act[nt] ? fb0[t*FHC + ncol[nt]] : 0.0f;
    }

    const unsigned short* aptr0 = DRbf + ((size_t)(b*NATC + ns[lc]))*1600 + lg*8;
    const unsigned short* bptr0[4];
    #pragma unroll
    for (int nt = 0; nt < 4; ++nt)
        bptr0[nt] = act[nt] ? (w0t + ((size_t)(t*FHC + ncol[nt]))*1600 + lg*8) : w0t;

    f32x4 acc[4];
    #pragma unroll
    for (int nt = 0; nt < 4; ++nt){
        acc[nt][0] = bias0[nt]; acc[nt][1] = bias0[nt];
        acc[nt][2] = bias0[nt]; acc[nt][3] = bias0[nt];
    }
    #pragma unroll 2
    for (int ks = 0; ks < 50; ++ks){
        bf16x8 af = *(const bf16x8*)(aptr0 + ks*32);
        #pragma unroll
        for (int nt = 0; nt < 4; ++nt){
            if (act[nt]){
                bf16x8 bfg = *(const bf16x8*)(bptr0[nt] + ks*32);
                acc[nt] = __builtin_amdgcn_mfma_f32_16x16x32_bf16(af, bfg, acc[nt], 0, 0, 0);
            }
        }
    }
    float h0r[4][4];
    #pragma unroll
    for (int nt = 0; nt < 4; ++nt){
        #pragma unroll
        for (int i = 0; i < 4; ++i){
            int row = lg*4 + i;
            if (act[nt]){
                h0r[nt][i] = fast_tanh(acc[nt][i]);
                hA[row][ncol[nt]] = f2bf(h0r[nt][i]);
            } else {
                h0r[nt][i] = 0.0f;
                hA[row][ncol[nt]] = 0;
            }
        }
    }
    __syncthreads();

    f32x4 acc1[4];
    #pragma unroll
    for (int nt = 0; nt < 4; ++nt){
        float bv = act[nt] ? fb1[t*FHC + ncol[nt]] : 0.0f;
        acc1[nt][0] = bv; acc1[nt][1] = bv; acc1[nt][2] = bv; acc1[nt][3] = bv;
    }
    const unsigned short* b1p[4];
    #pragma unroll
    for (int nt = 0; nt < 4; ++nt)
        b1p[nt] = act[nt] ? (w1t + ((size_t)(t*FHC + ncol[nt]))*KPAD + lg*8) : w1t;
    #pragma unroll
    for (int ks = 0; ks < 8; ++ks){
        bf16x8 af = *(const bf16x8*)&hA[lc][ks*32 + lg*8];
        #pragma unroll
        for (int nt = 0; nt < 4; ++nt){
            if (act[nt]){
                bf16x8 bfg = *(const bf16x8*)(b1p[nt] + ks*32);
                acc1[nt] = __builtin_amdgcn_mfma_f32_16x16x32_bf16(af, bfg, acc1[nt], 0, 0, 0);
            }
        }
    }
    float h1r[4][4];
    #pragma unroll
    for (int nt = 0; nt < 4; ++nt){
        #pragma unroll
        for (int i = 0; i < 4; ++i){
            int row = lg*4 + i;
            if (act[nt]){
                h1r[nt][i] = fast_tanh(acc1[nt][i]) + h0r[nt][i];
                hB[row][ncol[nt]] = f2bf(h1r[nt][i]);
            } else {
                h1r[nt][i] = 0.0f;
                hB[row][ncol[nt]] = 0;
            }
        }
    }
    __syncthreads();

    f32x4 acc2[4];
    #pragma unroll
    for (int nt = 0; nt < 4; ++nt){
        float bv = act[nt] ? fb2[t*FHC + ncol[nt]] : 0.0f;
        acc2[nt][0] = bv; acc2[nt][1] = bv; acc2[nt][2] = bv; acc2[nt][3] = bv;
    }
    const unsigned short* b2p[4];
    #pragma unroll
    for (int nt = 0; nt < 4; ++nt)
        b2p[nt] = act[nt] ? (w2t + ((size_t)(t*FHC + ncol[nt]))*KPAD + lg*8) : w2t;
    #pragma unroll
    for (int ks = 0; ks < 8; ++ks){
        bf16x8 af = *(const bf16x8*)&hB[lc][ks*32 + lg*8];
        #pragma unroll
        for (int nt = 0; nt < 4; ++nt){
            if (act[nt]){
                bf16x8 bfg = *(const bf16x8*)(b2p[nt] + ks*32);
                acc2[nt] = __builtin_amdgcn_mfma_f32_16x16x32_bf16(af, bfg, acc2[nt], 0, 0, 0);
            }
        }
    }

    float p0 = 0.0f, p1 = 0.0f, p2 = 0.0f, p3 = 0.0f;
    #pragma unroll
    for (int nt = 0; nt < 4; ++nt){
        if (act[nt]){
            float wfv = fWf[t*FHC + ncol[nt]];
            float h;
            h = fast_tanh(acc2[nt][0]) + h1r[nt][0]; p0 = fmaf(h, wfv, p0);
            h = fast_tanh(acc2[nt][1]) + h1r[nt][1]; p1 = fmaf(h, wfv, p1);
            h = fast_tanh(acc2[nt][2]) + h1r[nt][2]; p2 = fmaf(h, wfv, p2);
            h = fast_tanh(acc2[nt][3]) + h1r[nt][3]; p3 = fmaf(h, wfv, p3);
        }
    }
    #pragma unroll
    for (int off = 1; off < 16; off <<= 1){
        p0 += __shfl_xor(p0, off);
        p1 += __shfl_xor(p1, off);
        p2 += __shfl_xor(p2, off);
        p3 += __shfl_xor(p3, off);
    }
    if (lc == 0){
        epart[w][lg*4 + 0] = p0;
        epart[w][lg*4 + 1] = p1;
        epart[w][lg*4 + 2] = p2;
        epart[w][lg*4 + 3] = p3;
    }
    __syncthreads();
    if (tid < 16){
        float e = fbf[t] + epart[0][tid] + epart[1][tid] + epart[2][tid] + epart[3][tid];
        float ee = 0.0f;
        if (tid < na){
            out[4 + b*NATC + ns[tid]] = e;
            ee = e;
        }
        #pragma unroll
        for (int off = 8; off >= 1; off >>= 1) ee += __shfl_down(ee, off, 16);
        if (tid == 0) atomicAdd(&out[b], ee);
    }
}

extern "C" void kernel_launch(void* const* d_in, const int* in_sizes, int n_in,
                              void* d_out, int out_size, void* d_ws, size_t ws_size,
                              hipStream_t stream)
{
    (void)in_sizes; (void)n_in; (void)out_size; (void)ws_size;
    const int*   tmap = (const int*)d_in[1];
    const float* imdr = (const float*)d_in[3];
    const float* davg = (const float*)d_in[5];
    const float* dstd = (const float*)d_in[6];
    const float* tv   = (const float*)d_in[7];
    const float* tW0  = (const float*)d_in[8];
    const float* tb0  = (const float*)d_in[9];
    const float* eW0  = (const float*)d_in[10];
    const float* eb0  = (const float*)d_in[11];
    const float* eW1  = (const float*)d_in[12];
    const float* eb1  = (const float*)d_in[13];
    const float* eW2  = (const float*)d_in[14];
    const float* eb2  = (const float*)d_in[15];
    const float* fW0  = (const float*)d_in[16];
    const float* fb0  = (const float*)d_in[17];
    const float* fW1  = (const float*)d_in[18];
    const float* fb1  = (const float*)d_in[19];
    const float* fW2  = (const float*)d_in[20];
    const float* fb2  = (const float*)d_in[21];
    const float* fWf  = (const float*)d_in[22];
    const float* fbf  = (const float*)d_in[23];
    float* out = (float*)d_out;

    char* ws = (char*)d_ws;
    int*   counts = (int*)ws;
    int*   idx    = (int*)(ws + 64);
    unsigned short* DRbf = (unsigned short*)(ws + 16384);
    unsigned short* w0t  = DRbf + (size_t)BATCH*NATC*1600;        // 13,107,200 B
    unsigned short* w1t  = w0t + (size_t)2*FHC*1600;              // 1,536,000 B
    unsigned short* w2t  = w1t + (size_t)2*FHC*KPAD;              // 245,760 B
    unsigned short* ew2t = w2t + (size_t)2*FHC*KPAD;              // 245,760 B
    float* tf_g          = (float*)(ew2t + 112*64);               // 14,336 B

    hipMemsetAsync(d_out, 0, 4*sizeof(float), stream);
    part_kernel<<<1, 256, 0, stream>>>(tmap, idx, counts);
    prep_kernel<<<1, 256, 0, stream>>>(tv, tW0, tb0, eW2, ew2t, tf_g);
    transp_kernel<<<2*25*4, 256, 0, stream>>>(fW0, w0t, 1600, FHC, 1600, 25, 4);
    transp_kernel<<<2*4*4,  256, 0, stream>>>(fW1, w1t, FHC, FHC, KPAD, 4, 4);
    transp_kernel<<<2*4*4,  256, 0, stream>>>(fW2, w2t, FHC, FHC, KPAD, 4, 4);
    embed_kernel<<<BATCH*NATC, 256, 0, stream>>>(
        (const float4*)imdr, (const float4*)davg, (const float4*)dstd, tmap,
        tf_g, eW0, eb0, eW1, eb1, eb2, ew2t, DRbf);
    fitm_kernel<<<512, 256, 0, stream>>>(
        DRbf, idx, counts, w0t, w1t, w2t, fb0, fb1, fb2, fWf, fbf, out);
}

// Round 4
// 413.897 us; speedup vs baseline: 1.8218x; 1.0370x over previous
//
#include <hip/hip_runtime.h>
#include <hip/hip_bf16.h>

#define NATC  1024
#define BATCH 4
#define MNTC  200
#define M1C   100
#define M2C   16
#define FHC   240
#define KPAD  256
#define HSTR  264   // fitm LDS h row stride (bf16): 528B = 16B-aligned
#define H1STR 40    // embed h1 stage stride (bf16): 80B rows, 2-way-free banks
#define H2STR 72    // embed h2 stage stride (bf16): 144B rows, 2-way-free banks

typedef __attribute__((ext_vector_type(8))) short bf16x8;
typedef __attribute__((ext_vector_type(4))) float f32x4;

__device__ __forceinline__ float fast_tanh(float x){
    float e = __expf(2.0f * x);
    float r = __fdividef(1.0f, e + 1.0f);
    return fmaf(-2.0f, r, 1.0f);
}

__device__ __forceinline__ unsigned short f2bf(float x){
    __hip_bfloat16 h = __float2bfloat16(x);
    return *reinterpret_cast<unsigned short*>(&h);
}

__device__ __forceinline__ float bf2f(unsigned short u){
    unsigned int v = ((unsigned int)u) << 16;
    return *reinterpret_cast<float*>(&v);
}

__device__ __forceinline__ unsigned int pack2(float a, float b){
    return (unsigned int)f2bf(a) | ((unsigned int)f2bf(b) << 16);
}

// ---------------- partition atoms by type (deterministic) ----------------
__global__ __launch_bounds__(256) void part_kernel(const int* __restrict__ tmap,
                                                   int* __restrict__ idx,
                                                   int* __restrict__ counts){
    __shared__ int s0[256], s1[256];
    const int tid = threadIdx.x;
    int ty[4]; int c0 = 0, c1 = 0;
    #pragma unroll
    for (int r = 0; r < 4; ++r){
        ty[r] = tmap[tid*4 + r];
        if (ty[r] == 0) c0++; else c1++;
    }
    s0[tid] = c0; s1[tid] = c1;
    __syncthreads();
    for (int off = 1; off < 256; off <<= 1){
        int v0 = (tid >= off) ? s0[tid-off] : 0;
        int v1 = (tid >= off) ? s1[tid-off] : 0;
        __syncthreads();
        s0[tid] += v0; s1[tid] += v1;
        __syncthreads();
    }
    int e0 = s0[tid] - c0, e1 = s1[tid] - c1;
    #pragma unroll
    for (int r = 0; r < 4; ++r){
        int n = tid*4 + r;
        if (ty[r] == 0) idx[e0++] = n; else idx[NATC + e1++] = n;
    }
    if (tid == 255){ counts[0] = s0[255]; counts[1] = s1[255]; }
}

// ---------------- tiled transpose: src fp32 [2][K][N] -> dst bf16 [2][N][Kpad] ----------------
__global__ __launch_bounds__(256) void transp_kernel(const float* __restrict__ src,
                                                     unsigned short* __restrict__ dst,
                                                     int K, int N, int Kpad, int nkt, int nnt){
    __shared__ float tile[64][65];
    const int tid = threadIdx.x;
    int bid = blockIdx.x;
    const int t  = bid / (nkt*nnt);
    bid -= t*nkt*nnt;
    const int kt = bid / nnt;
    const int nt = bid - kt*nnt;
    const float* s = src + (size_t)t*K*N;
    unsigned short* d = dst + (size_t)t*N*Kpad;

    const int c  = tid & 63;
    const int rg = tid >> 6;
    #pragma unroll
    for (int p = 0; p < 16; ++p){
        int row = p*4 + rg;
        int gr = kt*64 + row, gc = nt*64 + c;
        tile[row][c] = (gr < K && gc < N) ? s[(size_t)gr*N + gc] : 0.0f;
    }
    __syncthreads();
    const int nn0 = tid >> 3;
    const int k8  = (tid & 7) * 8;
    #pragma unroll
    for (int p = 0; p < 2; ++p){
        int nn = p*32 + nn0;
        int gn = nt*64 + nn;
        int gk = kt*64 + k8;
        if (gn < N && gk < Kpad){
            unsigned short v[8];
            #pragma unroll
            for (int j = 0; j < 8; ++j) v[j] = f2bf(tile[k8+j][nn]);
            *(bf16x8*)(d + (size_t)gn*Kpad + gk) = *(bf16x8*)v;
        }
    }
}

// ---------------- small prep: type features + ew1t [64][32] + ew2t [112][64] ----------------
__global__ __launch_bounds__(256) void prep_kernel(const float* __restrict__ tv,
                                                   const float* __restrict__ tW0,
                                                   const float* __restrict__ tb0,
                                                   const float* __restrict__ eW1,
                                                   const float* __restrict__ eW2,
                                                   unsigned short* __restrict__ ew1t,
                                                   unsigned short* __restrict__ ew2t,
                                                   float* __restrict__ tf_g){
    const int tid = threadIdx.x;
    if (tid < 16){
        int t = tid >> 3, f = tid & 7;
        float s = tb0[f];
        #pragma unroll
        for (int p = 0; p < 4; ++p) s = fmaf(tv[t*4+p], tW0[p*8+f], s);
        tf_g[tid] = fast_tanh(s) + tv[t*4 + (f & 3)];
    }
    for (int i = tid; i < 112*64; i += 256){
        int n = i >> 6, k = i & 63;
        ew2t[i] = (n < M1C && k < 50) ? f2bf(eW2[(size_t)k*M1C + n]) : (unsigned short)0;
    }
    for (int i = tid; i < 64*32; i += 256){
        int n = i >> 5, k = i & 31;
        ew1t[i] = (n < 50 && k < 25) ? f2bf(eW1[(size_t)k*50 + n]) : (unsigned short)0;
    }
}

// ---------------- embedding: Ri+L0 per-thread fp32, L1+L2 via MFMA ----------------
__global__ __launch_bounds__(256, 2) void embed_kernel(
    const float4* __restrict__ imdr,
    const float4* __restrict__ davg,
    const float4* __restrict__ dstd,
    const int*    __restrict__ tmap,
    const float*  __restrict__ tf_g,
    const float*  __restrict__ eW0,
    const float*  __restrict__ eb0,
    const float*  __restrict__ eb1,
    const float*  __restrict__ eb2,
    const unsigned short* __restrict__ ew1t,
    const unsigned short* __restrict__ ew2t,
    unsigned short* __restrict__ DRout)
{
    __shared__ __align__(16) float Rif[256][4];                 // 4 KB
    __shared__ __align__(16) unsigned short H1s[256][H1STR];    // 20 KB (overlaid by xyz later)
    __shared__ __align__(16) unsigned short H2s[256][H2STR];    // 36.9 KB

    const int tid = threadIdx.x;
    const int a   = blockIdx.x;
    const int n0  = a & (NATC - 1);
    const int itype = tmap[n0];
    const int j = tid;

    // ---------- phase A: Ri + L0 (fp32 per-thread), stage h1 bf16 ----------
    {
        unsigned int* rowp = (unsigned int*)&H1s[j][0];
        if (j < MNTC){
            float4 dr = imdr[(size_t)a*MNTC + j];
            float r  = dr.x;
            float rs = (r > 1e-5f) ? r : 1.0f;
            float ir = __fdividef(1.0f, rs);
            float u  = (r - 0.5f) * (1.0f/5.5f);
            float u2 = u*u, u3 = u2*u;
            float smid = ir * (u3 * (-6.0f*u2 + 15.0f*u - 10.0f) + 1.0f);
            float S = 0.0f;
            if (r > 0.0f && r < 0.5f)       S = ir;
            else if (r >= 0.5f && r < 6.0f) S = smid;
            bool msk = fabsf(r) > 1e-5f;
            float R0 = S;
            float R1 = msk ? S * dr.y * ir : 0.0f;
            float R2 = msk ? S * dr.z * ir : 0.0f;
            float R3 = msk ? S * dr.w * ir : 0.0f;
            float4 av = davg[itype*MNTC + j];
            float4 sv = dstd[itype*MNTC + j];
            float rin0 = __fdividef(R0 - av.x, sv.x);
            float rin1 = __fdividef(R1 - av.y, sv.y);
            float rin2 = __fdividef(R2 - av.z, sv.z);
            float rin3 = __fdividef(R3 - av.w, sv.w);
            Rif[j][0] = rin0; Rif[j][1] = rin1; Rif[j][2] = rin2; Rif[j][3] = rin3;

            float xf[8];
            const int tb = (j >= 100) ? 8 : 0;
            #pragma unroll
            for (int f = 0; f < 8; ++f) xf[f] = tf_g[tb + f];

            float h1[25];
            #pragma unroll
            for (int o = 0; o < 25; ++o) h1[o] = fmaf(rin0, eW0[o], eb0[o]);
            #pragma unroll
            for (int k = 0; k < 8; ++k){
                float hv = xf[k];
                #pragma unroll
                for (int o = 0; o < 25; ++o) h1[o] = fmaf(hv, eW0[(k+1)*25 + o], h1[o]);
            }
            #pragma unroll
            for (int o = 0; o < 25; ++o) h1[o] = fast_tanh(h1[o]);

            #pragma unroll
            for (int c = 0; c < 12; ++c) rowp[c] = pack2(h1[2*c], h1[2*c+1]);
            rowp[12] = (unsigned int)f2bf(h1[24]);
            #pragma unroll
            for (int c = 13; c < 20; ++c) rowp[c] = 0u;
        } else {
            Rif[j][0] = 0.0f; Rif[j][1] = 0.0f; Rif[j][2] = 0.0f; Rif[j][3] = 0.0f;
            #pragma unroll
            for (int c = 0; c < 20; ++c) rowp[c] = 0u;
        }
    }
    __syncthreads();

    const int lane = tid & 63;
    const int w    = tid >> 6;
    const int lc   = lane & 15;
    const int lg   = lane >> 4;

    // ---------- L1 via MFMA: M=256, K=32(pad25), N=64(pad50) ----------
    #pragma unroll
    for (int mi = 0; mi < 4; ++mi){
        const int mt = w + mi*4;
        bf16x8 af = *(const bf16x8*)&H1s[mt*16 + lc][lg*8];
        const int rbase = mt*16 + lg*4;
        #pragma unroll
        for (int nt = 0; nt < 4; ++nt){
            const int n = nt*16 + lc;
            const bool live = (n < 50);
            float bv = live ? eb1[n] : 0.0f;
            f32x4 c;
            c[0] = bv; c[1] = bv; c[2] = bv; c[3] = bv;
            bf16x8 bfr = *(const bf16x8*)(ew1t + n*32 + lg*8);
            c = __builtin_amdgcn_mfma_f32_16x16x32_bf16(af, bfr, c, 0, 0, 0);
            const int rc = n % 25;
            #pragma unroll
            for (int i = 0; i < 4; ++i){
                const int row = rbase + i;
                unsigned short v = 0;
                if (live) v = f2bf(fast_tanh(c[i]) + bf2f(H1s[row][rc]));
                H2s[row][n] = v;
            }
        }
    }
    __syncthreads();   // H2s complete; H1s reads done (xyz overlays H1s below)

    // ---------- L2 via MFMA (M=256, K=64, N=112) + xyz reduce ----------
    float* xyzp = (float*)&H1s[0][0];        // [4][4][112] = 7168 B (overlays dead H1s)
    float* xyzs = xyzp + 4*4*112;            // [4][112]    = 1792 B

    float bias[7];
    #pragma unroll
    for (int nt = 0; nt < 7; ++nt){
        int cg = nt*16 + lc;
        bias[nt] = (cg < M1C) ? eb2[cg] : 0.0f;
    }

    float xacc[7][4];
    #pragma unroll
    for (int nt = 0; nt < 7; ++nt)
        #pragma unroll
        for (int d = 0; d < 4; ++d) xacc[nt][d] = 0.0f;

    #pragma unroll
    for (int mi = 0; mi < 4; ++mi){
        const int mt = w + mi*4;
        const int rbase = mt*16 + lg*4;
        float4 rj[4];
        #pragma unroll
        for (int i = 0; i < 4; ++i) rj[i] = *(const float4*)&Rif[rbase + i][0];
        const unsigned short* arow = &H2s[mt*16 + lc][0];
        bf16x8 a0 = *(const bf16x8*)(arow + lg*8);
        bf16x8 a1 = *(const bf16x8*)(arow + 32 + lg*8);
        #pragma unroll
        for (int nt = 0; nt < 7; ++nt){
            const unsigned short* bp = ew2t + (size_t)(nt*16 + lc)*64 + lg*8;
            bf16x8 b0 = *(const bf16x8*)(bp);
            bf16x8 b1 = *(const bf16x8*)(bp + 32);
            f32x4 c;
            c[0] = bias[nt]; c[1] = bias[nt]; c[2] = bias[nt]; c[3] = bias[nt];
            c = __builtin_amdgcn_mfma_f32_16x16x32_bf16(a0, b0, c, 0, 0, 0);
            c = __builtin_amdgcn_mfma_f32_16x16x32_bf16(a1, b1, c, 0, 0, 0);
            const int cg = nt*16 + lc;
            const int rc = (cg >= 100) ? cg - 100 : ((cg >= 50) ? cg - 50 : cg);
            #pragma unroll
            for (int i = 0; i < 4; ++i){
                float g = fast_tanh(c[i]) + bf2f(H2s[rbase + i][rc]);
                xacc[nt][0] = fmaf(g, rj[i].x, xacc[nt][0]);
                xacc[nt][1] = fmaf(g, rj[i].y, xacc[nt][1]);
                xacc[nt][2] = fmaf(g, rj[i].z, xacc[nt][2]);
                xacc[nt][3] = fmaf(g, rj[i].w, xacc[nt][3]);
            }
        }
    }
    #pragma unroll
    for (int nt = 0; nt < 7; ++nt){
        #pragma unroll
        for (int d = 0; d < 4; ++d){
            float v = xacc[nt][d];
            v += __shfl_xor(v, 16);
            v += __shfl_xor(v, 32);
            if (lane < 16) xyzp[((w*4 + d)*112) + nt*16 + lc] = v;
        }
    }
    __syncthreads();

    for (int i = tid; i < 4*112; i += 256){
        int d = i / 112, m = i - d*112;
        xyzs[d*112 + m] = (xyzp[(0*4+d)*112 + m] + xyzp[(1*4+d)*112 + m] +
                           xyzp[(2*4+d)*112 + m] + xyzp[(3*4+d)*112 + m])
                          * (1.0f / (float)MNTC);
    }
    __syncthreads();

    for (int i = tid; i < M1C*M2C; i += 256){
        int m = i >> 4, q = i & 15;
        float s = 0.0f;
        #pragma unroll
        for (int d = 0; d < 4; ++d) s = fmaf(xyzs[d*112 + m], xyzs[d*112 + q], s);
        DRout[(size_t)a*(M1C*M2C) + i] = f2bf(s);
    }
}

// ---------------- fitting net: bf16 MFMA, 16 atoms/block, 8 waves (2 tiles each) ----------------
__global__ __launch_bounds__(512) void fitm_kernel(
    const unsigned short* __restrict__ DRbf,   // [4096][1600] bf16
    const int*   __restrict__ idx,
    const int*   __restrict__ counts,
    const unsigned short* __restrict__ w0t,    // [2][240][1600]
    const unsigned short* __restrict__ w1t,    // [2][240][256]
    const unsigned short* __restrict__ w2t,    // [2][240][256]
    const float* __restrict__ fb0,
    const float* __restrict__ fb1,
    const float* __restrict__ fb2,
    const float* __restrict__ fWf,
    const float* __restrict__ fbf,
    float* __restrict__ out)     // out[0..3]=Etot, out[4..]=Ei
{
    const int bid = blockIdx.x;
    const int g = bid & 63;
    const int t = (bid >> 6) & 1;
    const int b = bid >> 7;
    const int cnt  = counts[t];
    const int base = g * 16;
    if (base >= cnt) return;
    const int na = min(16, cnt - base);

    __shared__ int ns[16];
    __shared__ __align__(16) unsigned short hA[16][HSTR];
    __shared__ __align__(16) unsigned short hB[16][HSTR];
    __shared__ float epart[8][16];

    const int tid  = threadIdx.x;
    const int lane = tid & 63;
    const int w    = tid >> 6;       // wave 0..7, owns n-cols [w*32, w*32+32)
    if (tid < 16) ns[tid] = idx[t*NATC + base + ((tid < na) ? tid : 0)];
    __syncthreads();

    const int lc = lane & 15;
    const int lg = lane >> 4;

    int   ncol[2];  bool act[2];  float bias0[2];
    #pragma unroll
    for (int nt = 0; nt < 2; ++nt){
        ncol[nt] = w*32 + nt*16 + lc;
        act[nt]  = (w*32 + nt*16) < FHC;     // wave-uniform
        bias0[nt] = act[nt] ? fb0[t*FHC + ncol[nt]] : 0.0f;
    }

    const unsigned short* aptr0 = DRbf + ((size_t)(b*NATC + ns[lc]))*1600 + lg*8;
    const unsigned short* bptr0[2];
    #pragma unroll
    for (int nt = 0; nt < 2; ++nt)
        bptr0[nt] = act[nt] ? (w0t + ((size_t)(t*FHC + ncol[nt]))*1600 + lg*8) : w0t;

    // ---- L0: 1600 -> 240 ----
    f32x4 acc[2];
    #pragma unroll
    for (int nt = 0; nt < 2; ++nt){
        acc[nt][0] = bias0[nt]; acc[nt][1] = bias0[nt];
        acc[nt][2] = bias0[nt]; acc[nt][3] = bias0[nt];
    }
    #pragma unroll 4
    for (int ks = 0; ks < 50; ++ks){
        bf16x8 af = *(const bf16x8*)(aptr0 + ks*32);
        #pragma unroll
        for (int nt = 0; nt < 2; ++nt){
            if (act[nt]){
                bf16x8 bfg = *(const bf16x8*)(bptr0[nt] + ks*32);
                acc[nt] = __builtin_amdgcn_mfma_f32_16x16x32_bf16(af, bfg, acc[nt], 0, 0, 0);
            }
        }
    }
    float h0r[2][4];
    #pragma unroll
    for (int nt = 0; nt < 2; ++nt){
        #pragma unroll
        for (int i = 0; i < 4; ++i){
            int row = lg*4 + i;
            if (act[nt]){
                h0r[nt][i] = fast_tanh(acc[nt][i]);
                hA[row][ncol[nt]] = f2bf(h0r[nt][i]);
            } else {
                h0r[nt][i] = 0.0f;
                hA[row][ncol[nt]] = 0;     // cols 240..255 zero pad
            }
        }
    }
    __syncthreads();

    // ---- L1: 240 -> 240 (+res), K padded to 256 ----
    f32x4 acc1[2];
    #pragma unroll
    for (int nt = 0; nt < 2; ++nt){
        float bv = act[nt] ? fb1[t*FHC + ncol[nt]] : 0.0f;
        acc1[nt][0] = bv; acc1[nt][1] = bv; acc1[nt][2] = bv; acc1[nt][3] = bv;
    }
    const unsigned short* b1p[2];
    #pragma unroll
    for (int nt = 0; nt < 2; ++nt)
        b1p[nt] = act[nt] ? (w1t + ((size_t)(t*FHC + ncol[nt]))*KPAD + lg*8) : w1t;
    #pragma unroll
    for (int ks = 0; ks < 8; ++ks){
        bf16x8 af = *(const bf16x8*)&hA[lc][ks*32 + lg*8];
        #pragma unroll
        for (int nt = 0; nt < 2; ++nt){
            if (act[nt]){
                bf16x8 bfg = *(const bf16x8*)(b1p[nt] + ks*32);
                acc1[nt] = __builtin_amdgcn_mfma_f32_16x16x32_bf16(af, bfg, acc1[nt], 0, 0, 0);
            }
        }
    }
    float h1r[2][4];
    #pragma unroll
    for (int nt = 0; nt < 2; ++nt){
        #pragma unroll
        for (int i = 0; i < 4; ++i){
            int row = lg*4 + i;
            if (act[nt]){
                h1r[nt][i] = fast_tanh(acc1[nt][i]) + h0r[nt][i];
                hB[row][ncol[nt]] = f2bf(h1r[nt][i]);
            } else {
                h1r[nt][i] = 0.0f;
                hB[row][ncol[nt]] = 0;
            }
        }
    }
    __syncthreads();

    // ---- L2: 240 -> 240 (+res) ----
    f32x4 acc2[2];
    #pragma unroll
    for (int nt = 0; nt < 2; ++nt){
        float bv = act[nt] ? fb2[t*FHC + ncol[nt]] : 0.0f;
        acc2[nt][0] = bv; acc2[nt][1] = bv; acc2[nt][2] = bv; acc2[nt][3] = bv;
    }
    const unsigned short* b2p[2];
    #pragma unroll
    for (int nt = 0; nt < 2; ++nt)
        b2p[nt] = act[nt] ? (w2t + ((size_t)(t*FHC + ncol[nt]))*KPAD + lg*8) : w2t;
    #pragma unroll
    for (int ks = 0; ks < 8; ++ks){
        bf16x8 af = *(const bf16x8*)&hB[lc][ks*32 + lg*8];
        #pragma unroll
        for (int nt = 0; nt < 2; ++nt){
            if (act[nt]){
                bf16x8 bfg = *(const bf16x8*)(b2p[nt] + ks*32);
                acc2[nt] = __builtin_amdgcn_mfma_f32_16x16x32_bf16(af, bfg, acc2[nt], 0, 0, 0);
            }
        }
    }

    // ---- final: e = sum_n h2*wf + fbf ----
    float p0 = 0.0f, p1 = 0.0f, p2 = 0.0f, p3 = 0.0f;
    #pragma unroll
    for (int nt = 0; nt < 2; ++nt){
        if (act[nt]){
            float wfv = fWf[t*FHC + ncol[nt]];
            float h;
            h = fast_tanh(acc2[nt][0]) + h1r[nt][0]; p0 = fmaf(h, wfv, p0);
            h = fast_tanh(acc2[nt][1]) + h1r[nt][1]; p1 = fmaf(h, wfv, p1);
            h = fast_tanh(acc2[nt][2]) + h1r[nt][2]; p2 = fmaf(h, wfv, p2);
            h = fast_tanh(acc2[nt][3]) + h1r[nt][3]; p3 = fmaf(h, wfv, p3);
        }
    }
    #pragma unroll
    for (int off = 1; off < 16; off <<= 1){
        p0 += __shfl_xor(p0, off);
        p1 += __shfl_xor(p1, off);
        p2 += __shfl_xor(p2, off);
        p3 += __shfl_xor(p3, off);
    }
    if (lc == 0){
        epart[w][lg*4 + 0] = p0;
        epart[w][lg*4 + 1] = p1;
        epart[w][lg*4 + 2] = p2;
        epart[w][lg*4 + 3] = p3;
    }
    __syncthreads();
    if (tid < 16){
        float e = fbf[t];
        #pragma unroll
        for (int ww = 0; ww < 8; ++ww) e += epart[ww][tid];
        float ee = 0.0f;
        if (tid < na){
            out[4 + b*NATC + ns[tid]] = e;
            ee = e;
        }
        #pragma unroll
        for (int off = 8; off >= 1; off >>= 1) ee += __shfl_down(ee, off, 16);
        if (tid == 0) atomicAdd(&out[b], ee);
    }
}

extern "C" void kernel_launch(void* const* d_in, const int* in_sizes, int n_in,
                              void* d_out, int out_size, void* d_ws, size_t ws_size,
                              hipStream_t stream)
{
    (void)in_sizes; (void)n_in; (void)out_size; (void)ws_size;
    const int*   tmap = (const int*)d_in[1];
    const float* imdr = (const float*)d_in[3];
    const float* davg = (const float*)d_in[5];
    const float* dstd = (const float*)d_in[6];
    const float* tv   = (const float*)d_in[7];
    const float* tW0  = (const float*)d_in[8];
    const float* tb0  = (const float*)d_in[9];
    const float* eW0  = (const float*)d_in[10];
    const float* eb0  = (const float*)d_in[11];
    const float* eW1  = (const float*)d_in[12];
    const float* eb1  = (const float*)d_in[13];
    const float* eW2  = (const float*)d_in[14];
    const float* eb2  = (const float*)d_in[15];
    const float* fW0  = (const float*)d_in[16];
    const float* fb0  = (const float*)d_in[17];
    const float* fW1  = (const float*)d_in[18];
    const float* fb1  = (const float*)d_in[19];
    const float* fW2  = (const float*)d_in[20];
    const float* fb2  = (const float*)d_in[21];
    const float* fWf  = (const float*)d_in[22];
    const float* fbf  = (const float*)d_in[23];
    float* out = (float*)d_out;

    char* ws = (char*)d_ws;
    int*   counts = (int*)ws;
    int*   idx    = (int*)(ws + 64);
    unsigned short* DRbf = (unsigned short*)(ws + 16384);
    unsigned short* w0t  = DRbf + (size_t)BATCH*NATC*1600;        // 13,107,200 B
    unsigned short* w1t  = w0t + (size_t)2*FHC*1600;              // 1,536,000 B
    unsigned short* w2t  = w1t + (size_t)2*FHC*KPAD;              // 245,760 B
    unsigned short* ew2t = w2t + (size_t)2*FHC*KPAD;              // 245,760 B
    unsigned short* ew1t = ew2t + 112*64;                         // 14,336 B
    float* tf_g          = (float*)(ew1t + 64*32);                // 4,096 B

    hipMemsetAsync(d_out, 0, 4*sizeof(float), stream);
    part_kernel<<<1, 256, 0, stream>>>(tmap, idx, counts);
    prep_kernel<<<1, 256, 0, stream>>>(tv, tW0, tb0, eW1, eW2, ew1t, ew2t, tf_g);
    transp_kernel<<<2*25*4, 256, 0, stream>>>(fW0, w0t, 1600, FHC, 1600, 25, 4);
    transp_kernel<<<2*4*4,  256, 0, stream>>>(fW1, w1t, FHC, FHC, KPAD, 4, 4);
    transp_kernel<<<2*4*4,  256, 0, stream>>>(fW2, w2t, FHC, FHC, KPAD, 4, 4);
    embed_kernel<<<BATCH*NATC, 256, 0, stream>>>(
        (const float4*)imdr, (const float4*)davg, (const float4*)dstd, tmap,
        tf_g, eW0, eb0, eb1, eb2, ew1t, ew2t, DRbf);
    fitm_kernel<<<512, 512, 0, stream>>>(
        DRbf, idx, counts, w0t, w1t, w2t, fb0, fb1, fb2, fWf, fbf, out);
}